// Round 16
// baseline (179.422 us; speedup 1.0000x reference)
//
#include <hip/hip_runtime.h>

typedef __bf16 bf16;
typedef __bf16 bf16x4 __attribute__((ext_vector_type(4)));
typedef __bf16 bf16x8 __attribute__((ext_vector_type(8)));
typedef float f32x4 __attribute__((ext_vector_type(4)));

#define GL(p) ((const __attribute__((address_space(1))) void*)(p))
#define LD(p) ((__attribute__((address_space(3))) void*)(p))

static __device__ __forceinline__ void nt_store4(float* p, f32x4 v) {
    __builtin_nontemporal_store(v, (f32x4*)p);
}

// ------------- fused prep: cast x | transpose+cast W | RoPE tables ----------
__global__ __launch_bounds__(256) void k_prep(
    const float4* __restrict__ x4, bf16x4* __restrict__ o4,
    const float* __restrict__ W, bf16* __restrict__ Wt,
    float* __restrict__ cost, float* __restrict__ sint)
{
    __shared__ bf16 tile[64][65];
    const int bid = (int)blockIdx.x;
    const int t = threadIdx.x;
    if (bid < 2048) {
        for (int i = bid * 256 + t; i < 2097152; i += 2048 * 256) {
            float4 v = x4[i];
            bf16x4 o;
            o[0] = (bf16)v.x; o[1] = (bf16)v.y; o[2] = (bf16)v.z; o[3] = (bf16)v.w;
            o4[i] = o;
        }
    } else if (bid < 2560) {
        const int wid = bid - 2048;
        const int k0 = (wid & 15) * 64;
        const int n0 = (wid >> 4) * 64;
        const int c = t & 63, r4 = t >> 6;
#pragma unroll
        for (int p = 0; p < 16; ++p) {
            int r = p * 4 + r4;
            tile[r][c] = (bf16)W[(size_t)(k0 + r) * 2048 + n0 + c];
        }
        __syncthreads();
#pragma unroll
        for (int p = 0; p < 16; ++p) {
            int n = p * 4 + r4;
            Wt[(size_t)(n0 + n) * 1024 + k0 + c] = tile[c][n];
        }
    } else {
        int idx = (bid - 2560) * 256 + t;  // 32768
        int pos = idx >> 5, i = idx & 31;
        float freq = powf(10000.f, -(float)i / 32.f);
        float ang = (float)pos * freq;
        cost[idx] = cosf(ang);
        sint[idx] = sinf(ang);
    }
}

// ---------------- GEMM1: proj = Xb @ Wt^T, fused bias + RoPE ----------------
// R5-exact clean (measured ~35 us in R7). Standard [b][h][n][d] Qb/Kb layout.
__global__ __launch_bounds__(512) void k_gemm1(
    const bf16* __restrict__ Xb, const bf16* __restrict__ Wt,
    const float* __restrict__ bias,
    const float* __restrict__ cost, const float* __restrict__ sint,
    bf16* __restrict__ Qb, bf16* __restrict__ Kb)
{
    __shared__ bf16 lA[2][256 * 64];   // 64 KB
    __shared__ bf16 lB[2][128 * 64];   // 32 KB
    const int t = threadIdx.x;
    const int lane = t & 63;
    const int wave = t >> 6;
    const int wr = (wave >> 1) * 64;
    const int wc = (wave & 1) * 64;
    const int bm = (int)blockIdx.x * 256;
    const int bn = (int)blockIdx.y * 128;
    const int rl = lane & 15;
    const int hi = lane >> 4;

    f32x4 acc[4][4] = {};

#define STAGE1(kt, c) do {                                                              \
    _Pragma("unroll")                                                                   \
    for (int p = 0; p < 4; ++p) {                                                       \
        int e = t * 8 + p * 4096;                                                       \
        int row = e >> 6; int g = (e >> 3) & 7;                                         \
        __builtin_amdgcn_global_load_lds(                                               \
            GL(Xb + (size_t)(bm + row) * 1024 + (kt) * 64 + ((g ^ (row & 7)) << 3)),    \
            LD(&lA[c][e]), 16, 0, 0);                                                   \
    }                                                                                   \
    _Pragma("unroll")                                                                   \
    for (int p = 0; p < 2; ++p) {                                                       \
        int e = t * 8 + p * 4096;                                                       \
        int row = e >> 6; int g = (e >> 3) & 7;                                         \
        __builtin_amdgcn_global_load_lds(                                               \
            GL(Wt + (size_t)(bn + row) * 1024 + (kt) * 64 + ((g ^ (row & 7)) << 3)),    \
            LD(&lB[c][e]), 16, 0, 0);                                                   \
    }                                                                                   \
} while (0)

    STAGE1(0, 0);
    STAGE1(1, 1);
    asm volatile("s_waitcnt vmcnt(6)" ::: "memory");
    __builtin_amdgcn_sched_barrier(0);
    __builtin_amdgcn_s_barrier();
    asm volatile("" ::: "memory");

    for (int kt = 0; kt < 16; ++kt) {
        const int cur = kt & 1;
        bf16x8 af[2][4], bfr[2][4];
#pragma unroll
        for (int ks = 0; ks < 2; ++ks) {
#pragma unroll
            for (int m = 0; m < 4; ++m) {
                int R = wr + m * 16 + rl;
                af[ks][m] = *(const bf16x8*)&lA[cur][(R << 6) + (((ks * 4 + hi) ^ (R & 7)) << 3)];
            }
#pragma unroll
            for (int n = 0; n < 4; ++n) {
                int S = wc + n * 16 + rl;
                bfr[ks][n] = *(const bf16x8*)&lB[cur][(S << 6) + (((ks * 4 + hi) ^ (S & 7)) << 3)];
            }
        }
#pragma unroll
        for (int ks = 0; ks < 2; ++ks)
#pragma unroll
            for (int m = 0; m < 4; ++m)
#pragma unroll
                for (int n = 0; n < 4; ++n)
                    acc[m][n] = __builtin_amdgcn_mfma_f32_16x16x32_bf16(af[ks][m], bfr[ks][n], acc[m][n], 0, 0, 0);

        if (kt < 15) {
            __builtin_amdgcn_s_barrier();
            if (kt + 2 < 16) {
                STAGE1(kt + 2, cur);
                asm volatile("s_waitcnt vmcnt(6)" ::: "memory");
            } else {
                asm volatile("s_waitcnt vmcnt(0)" ::: "memory");
            }
            __builtin_amdgcn_sched_barrier(0);
            __builtin_amdgcn_s_barrier();
            asm volatile("" ::: "memory");
        }
    }
#undef STAGE1

#pragma unroll
    for (int m = 0; m < 4; ++m) {
#pragma unroll
        for (int n = 0; n < 4; ++n) {
            int colg = bn + wc + n * 16 + rl;
            float bv = bias[colg];
            int h = colg >> 7;
            int rem = colg & 127;
            int qk = rem >> 6;
            int dcol = rem & 63;
            int fi = dcol >> 1;
            float sgn = (dcol & 1) ? 1.f : -1.f;
            bf16* dstb = qk ? Kb : Qb;
#pragma unroll
            for (int r = 0; r < 4; ++r) {
                int rowg = bm + wr + m * 16 + hi * 4 + r;
                int pos = rowg & 1023, bidx = rowg >> 10;
                float val = acc[m][n][r] + bv;
                float part = __shfl_xor(val, 1);
                float cv = cost[pos * 32 + fi], sv = sint[pos * 32 + fi];
                float outv = val * cv + sgn * part * sv;
                dstb[(((size_t)(bidx * 16 + h)) * 1024 + pos) * 64 + dcol] = (bf16)outv;
            }
        }
    }
}

// ------- K_QK: full-row strip kernel -- ALL of out, fill-pattern stores -----
// Block = 16 Q-rows x full 1024 cols of one bh. K streamed in 64-row chunks
// (fully-causal chunks skipped -> penalty formula in store pass). Row buffer
// in LDS; store pass writes 4 KB contiguous per wave-instruction.
// LDS 78 KB -> 2 blocks/CU (compute of one overlaps stores of the other).
__global__ __launch_bounds__(256) void k_qk(
    const bf16* __restrict__ Qb, const bf16* __restrict__ Kb,
    const float* __restrict__ smask, float* __restrict__ out)
{
    __shared__ __align__(16) float obuf[16 * 1024];   // 64 KB
    __shared__ __align__(16) bf16 lK[64 * 64];        //  8 KB
    __shared__ __align__(16) bf16 lQ[16 * 64];        //  2 KB
    __shared__ float npen_l[1024];                    //  4 KB
    __shared__ float mpen_l[16];

    const int t = threadIdx.x;
    const int lane = t & 63, w = t >> 6;
    const int rl = lane & 15, hi = lane >> 4;
    const int bid = (int)blockIdx.x;      // 8192 = 8 xcd * 16 bh * 64 strips
    const int xcd = bid & 7;
    const int bh = xcd * 16 + ((bid >> 3) & 15);
    const int strip = bid >> 7;           // 0..63
    const int bm = strip * 16;
    const int b = bh >> 4;
    const int cstart = strip >> 2;        // first non-fully-causal 64-chunk
    const float NINF = 1.25e11f;
    const size_t qoff = (size_t)bh << 16;

    {   // mask tables
        f32x4 sv = *(const f32x4*)&smask[b * 1024 + t * 4];
        f32x4 nv;
#pragma unroll
        for (int r = 0; r < 4; ++r) nv[r] = 1.f - sv[r];
        *(f32x4*)&npen_l[t * 4] = nv;
        if (t < 16) mpen_l[t] = 1.f - smask[b * 1024 + bm + t];
    }

    // stage Q strip (16 rows x 64), pre-swizzled source, threads 0..127
    if (t < 128) {
        int row = t >> 3, c16 = t & 7;
        int se = (row << 6) + ((c16 ^ (row & 7)) << 3);
        __builtin_amdgcn_global_load_lds(GL(Qb + qoff + (size_t)bm * 64 + se),
                                         LD(&lQ[t * 8]), 16, 0, 0);
    }

    for (int c = cstart; c < 16; ++c) {
        // stage K chunk c (64 rows x 64), pre-swizzled source
#pragma unroll
        for (int p = 0; p < 2; ++p) {
            int e = t * 8 + p * 2048;
            int gr = e >> 3;
            int row = gr >> 3, c16 = gr & 7;
            int se = (row << 6) + ((c16 ^ (row & 7)) << 3);
            __builtin_amdgcn_global_load_lds(GL(Kb + qoff + (size_t)(c * 64) * 64 + se),
                                             LD(&lK[e]), 16, 0, 0);
        }
        __syncthreads();
        // MFMA: wave w owns col-frag i=w of this chunk (A=K rows, B=Q rows)
        f32x4 acc = {};
        const int R = w * 16 + rl;
#pragma unroll
        for (int ks = 0; ks < 2; ++ks) {
            bf16x8 a = *(const bf16x8*)&lK[(R << 6) + ((((ks << 2) + hi) ^ (R & 7)) << 3)];
            bf16x8 q = *(const bf16x8*)&lQ[(rl << 6) + ((((ks << 2) + hi) ^ (rl & 7)) << 3)];
            acc = __builtin_amdgcn_mfma_f32_16x16x32_bf16(a, q, acc, 0, 0, 0);
        }
        // value(lane,r): out row = rl, col = c*64 + w*16 + hi*4 + r
        int c0b = (c * 64 + w * 16 + hi * 4) * 4;       // byte col in row
        *(f32x4*)((char*)obuf + (rl << 12) + (c0b ^ ((rl & 15) << 4))) = acc;
        __syncthreads();   // writes visible + lK free for next chunk
    }

    // store pass: row `it` written as one contiguous 4 KB line
#pragma unroll
    for (int it = 0; it < 16; ++it) {
        int gcb = t * 4;                  // global col base
        int grow = bm + it;
        float mp = mpen_l[it];
        f32x4 np = *(const f32x4*)&npen_l[gcb];
        f32x4 vo;
        if (gcb >= cstart * 64) {
            f32x4 v = *(const f32x4*)((char*)obuf + (it << 12) + ((gcb * 4) ^ ((it & 15) << 4)));
#pragma unroll
            for (int r = 0; r < 4; ++r) {
                float pen = mp + np[r] + ((gcb + r < grow) ? 1.f : 0.f);
                vo[r] = v[r] * 0.125f - pen * NINF;
            }
        } else {
#pragma unroll
            for (int r = 0; r < 4; ++r) vo[r] = -(mp + np[r] + 1.f) * NINF;
        }
        nt_store4(&out[((size_t)bh << 20) + ((size_t)grow << 10) + gcb], vo);
    }
}

extern "C" void kernel_launch(void* const* d_in, const int* in_sizes, int n_in,
                              void* d_out, int out_size, void* d_ws, size_t ws_size,
                              hipStream_t stream) {
    (void)in_sizes; (void)n_in; (void)out_size; (void)ws_size;
    const float* x    = (const float*)d_in[0];
    const float* W    = (const float*)d_in[1];
    const float* bias = (const float*)d_in[2];
    const float* sm   = (const float*)d_in[3];
    float* out = (float*)d_out;

    char* ws = (char*)d_ws;
    size_t o = 0;
    bf16* Xb = (bf16*)(ws + o); o += 8388608ull * 2;
    bf16* Wt = (bf16*)(ws + o); o += 2097152ull * 2;
    bf16* Qb = (bf16*)(ws + o); o += 8388608ull * 2;
    bf16* Kb = (bf16*)(ws + o); o += 8388608ull * 2;
    float* cost = (float*)(ws + o); o += 32768ull * 4;
    float* sint = (float*)(ws + o); o += 32768ull * 4;

    hipLaunchKernelGGL(k_prep, dim3(2688), dim3(256), 0, stream,
                       (const float4*)x, (bf16x4*)Xb, W, Wt, cost, sint);
    hipLaunchKernelGGL(k_gemm1, dim3(32, 16), dim3(512), 0, stream,
                       Xb, Wt, bias, cost, sint, Qb, Kb);
    hipLaunchKernelGGL(k_qk, dim3(8192), dim3(256), 0, stream,
                       Qb, Kb, sm, out);
}

// Round 17
// 158.266 us; speedup vs baseline: 1.1337x; 1.1337x over previous
//
#include <hip/hip_runtime.h>

typedef __bf16 bf16;
typedef __bf16 bf16x4 __attribute__((ext_vector_type(4)));
typedef __bf16 bf16x8 __attribute__((ext_vector_type(8)));
typedef float f32x4 __attribute__((ext_vector_type(4)));

#define GL(p) ((const __attribute__((address_space(1))) void*)(p))
#define LD(p) ((__attribute__((address_space(3))) void*)(p))

static __device__ __forceinline__ void nt_store4(float* p, f32x4 v) {
    __builtin_nontemporal_store(v, (f32x4*)p);
}

// ------------- fused prep: cast x | transpose+cast W | RoPE tables ----------
__global__ __launch_bounds__(256) void k_prep(
    const float4* __restrict__ x4, bf16x4* __restrict__ o4,
    const float* __restrict__ W, bf16* __restrict__ Wt,
    float* __restrict__ cost, float* __restrict__ sint)
{
    __shared__ bf16 tile[64][65];
    const int bid = (int)blockIdx.x;
    const int t = threadIdx.x;
    if (bid < 2048) {
        for (int i = bid * 256 + t; i < 2097152; i += 2048 * 256) {
            float4 v = x4[i];
            bf16x4 o;
            o[0] = (bf16)v.x; o[1] = (bf16)v.y; o[2] = (bf16)v.z; o[3] = (bf16)v.w;
            o4[i] = o;
        }
    } else if (bid < 2560) {
        const int wid = bid - 2048;
        const int k0 = (wid & 15) * 64;
        const int n0 = (wid >> 4) * 64;
        const int c = t & 63, r4 = t >> 6;
#pragma unroll
        for (int p = 0; p < 16; ++p) {
            int r = p * 4 + r4;
            tile[r][c] = (bf16)W[(size_t)(k0 + r) * 2048 + n0 + c];
        }
        __syncthreads();
#pragma unroll
        for (int p = 0; p < 16; ++p) {
            int n = p * 4 + r4;
            Wt[(size_t)(n0 + n) * 1024 + k0 + c] = tile[c][n];
        }
    } else {
        int idx = (bid - 2560) * 256 + t;  // 32768
        int pos = idx >> 5, i = idx & 31;
        float freq = powf(10000.f, -(float)i / 32.f);
        float ang = (float)pos * freq;
        cost[idx] = cosf(ang);
        sint[idx] = sinf(ang);
    }
}

// ---------------- GEMM1: proj = Xb @ Wt^T, fused bias + RoPE ----------------
// 128x128 tile, 4 waves, BK=64, dbuf, T2 swizzle — 68 KB LDS => 2 blocks/CU
// so PS store drains overlap the other block's MFMA phases (R12 was 1/CU).
// Penalty-tile quarters (16 KB) fused at kt-boundaries, store-aware ledger:
//   prologue vmcnt(8); kt=0 -> 12; kt=1..13 -> 16; kt=14 -> 4.
__global__ __launch_bounds__(256) void k_gemm1(
    const bf16* __restrict__ Xb, const bf16* __restrict__ Wt,
    const float* __restrict__ bias,
    const float* __restrict__ cost, const float* __restrict__ sint,
    bf16* __restrict__ Qb, bf16* __restrict__ Kb,
    const float* __restrict__ smask, float* __restrict__ out)
{
    __shared__ bf16 lA[2][128 * 64];   // 32 KB
    __shared__ bf16 lB[2][128 * 64];   // 32 KB
    __shared__ float psm[4 * 256];     //  4 KB penalty-mask cache
    const int t = threadIdx.x;
    const int lane = t & 63;
    const int wave = t >> 6;
    const int wr = (wave >> 1) * 64;
    const int wc = (wave & 1) * 64;
    const int bm = (int)blockIdx.x * 128;   // 64 m-tiles
    const int bn = (int)blockIdx.y * 128;   // 16 n-tiles
    const int rl = lane & 15;
    const int hi = lane >> 4;
    const int flat = (int)blockIdx.y * 64 + (int)blockIdx.x;   // 0..1023
    const int qbase = flat * 14;            // quarter-tile index base
    const int tbase = qbase >> 2;           // first tile touched
    const float NINF = 1.25e11f;

    f32x4 acc[4][4] = {};

    // preload penalty masks for the 4 tiles this block's 14 quarters touch
#pragma unroll
    for (int i = 0; i < 4; ++i) {
        int tile = tbase + i;               // < 3584 guaranteed (max qi 14335)
        int bh2 = tile & 127;
        int k28 = tile >> 7;
        int tm = 1;
        while (k28 >= ((tm * (tm + 1)) >> 1)) ++tm;
        int tn = k28 - ((tm * (tm - 1)) >> 1);
        int b2 = bh2 >> 4;
        float v = (t < 128) ? smask[b2 * 1024 + tm * 128 + t]
                            : smask[b2 * 1024 + tn * 128 + (t - 128)];
        psm[i * 256 + t] = v;
    }

#define STAGE1(kt, c) do {                                                              \
    _Pragma("unroll")                                                                   \
    for (int p = 0; p < 4; ++p) {                                                       \
        int e = t * 8 + p * 2048;                                                       \
        int row = e >> 6; int g = (e >> 3) & 7;                                         \
        __builtin_amdgcn_global_load_lds(                                               \
            GL(Xb + (size_t)(bm + row) * 1024 + (kt) * 64 + ((g ^ (row & 7)) << 3)),    \
            LD(&lA[c][e]), 16, 0, 0);                                                   \
    }                                                                                   \
    _Pragma("unroll")                                                                   \
    for (int p = 0; p < 4; ++p) {                                                       \
        int e = t * 8 + p * 2048;                                                       \
        int row = e >> 6; int g = (e >> 3) & 7;                                         \
        __builtin_amdgcn_global_load_lds(                                               \
            GL(Wt + (size_t)(bn + row) * 1024 + (kt) * 64 + ((g ^ (row & 7)) << 3)),    \
            LD(&lB[c][e]), 16, 0, 0);                                                   \
    }                                                                                   \
} while (0)

    // penalty quarter-tile for boundary kt (kt = 0..13): qi = qbase + kt
#define PS(kt) do {                                                                     \
    int qi = qbase + (kt);                                                              \
    int tile = qi >> 2, q = qi & 3;                                                     \
    int bh2 = tile & 127;                                                               \
    int k28 = tile >> 7;                                                                \
    int tm = 1;                                                                         \
    while (k28 >= ((tm * (tm + 1)) >> 1)) ++tm;                                         \
    int tn = k28 - ((tm * (tm - 1)) >> 1);                                              \
    const float* pb = &psm[(tile - tbase) * 256];                                       \
    _Pragma("unroll")                                                                   \
    for (int s = 0; s < 4; ++s) {                                                       \
        int pos = s * 256 + t;               /* 0..1023 = 32 rows x 32 vec4 */          \
        int row = q * 32 + (pos >> 5), c4 = (pos & 31) << 2;                            \
        float smm = pb[row];                                                            \
        f32x4 smn = *(const f32x4*)&pb[128 + c4];                                       \
        f32x4 v;                                                                        \
        _Pragma("unroll")                                                               \
        for (int r = 0; r < 4; ++r) v[r] = (smm + smn[r] - 3.f) * NINF;                 \
        nt_store4(&out[((size_t)bh2 << 20) + ((size_t)(tm * 128 + row) << 10)           \
                       + tn * 128 + c4], v);                                            \
    }                                                                                   \
} while (0)

    STAGE1(0, 0);
    STAGE1(1, 1);
    asm volatile("s_waitcnt vmcnt(8)" ::: "memory");
    __builtin_amdgcn_sched_barrier(0);
    __builtin_amdgcn_s_barrier();
    asm volatile("" ::: "memory");

    for (int kt = 0; kt < 16; ++kt) {
        const int cur = kt & 1;
        bf16x8 af[2][4], bfr[2][4];
#pragma unroll
        for (int ks = 0; ks < 2; ++ks) {
#pragma unroll
            for (int m = 0; m < 4; ++m) {
                int R = wr + m * 16 + rl;
                af[ks][m] = *(const bf16x8*)&lA[cur][(R << 6) + (((ks * 4 + hi) ^ (R & 7)) << 3)];
            }
#pragma unroll
            for (int n = 0; n < 4; ++n) {
                int S = wc + n * 16 + rl;
                bfr[ks][n] = *(const bf16x8*)&lB[cur][(S << 6) + (((ks * 4 + hi) ^ (S & 7)) << 3)];
            }
        }
#pragma unroll
        for (int ks = 0; ks < 2; ++ks)
#pragma unroll
            for (int m = 0; m < 4; ++m)
#pragma unroll
                for (int n = 0; n < 4; ++n)
                    acc[m][n] = __builtin_amdgcn_mfma_f32_16x16x32_bf16(af[ks][m], bfr[ks][n], acc[m][n], 0, 0, 0);

        if (kt < 15) {
            __builtin_amdgcn_s_barrier();
            if (kt + 2 < 16) {
                STAGE1(kt + 2, cur);                 // 8 loads
                if (kt < 14) PS(kt);                 // 4 nt stores
                if (kt == 0) asm volatile("s_waitcnt vmcnt(12)" ::: "memory");
                else         asm volatile("s_waitcnt vmcnt(16)" ::: "memory");
            } else {
                // kt==14: outstanding = PS(13)[4] + loads(15)[8]; need loads(15)
                asm volatile("s_waitcnt vmcnt(4)" ::: "memory");
            }
            __builtin_amdgcn_sched_barrier(0);
            __builtin_amdgcn_s_barrier();
            asm volatile("" ::: "memory");
        }
    }
#undef STAGE1
#undef PS

    // epilogue: bias + interleaved RoPE + scatter into Qb/Kb [b][h][n][d]
#pragma unroll
    for (int m = 0; m < 4; ++m) {
#pragma unroll
        for (int n = 0; n < 4; ++n) {
            int colg = bn + wc + n * 16 + rl;
            float bv = bias[colg];
            int h = colg >> 7;
            int rem = colg & 127;
            int qk = rem >> 6;
            int dcol = rem & 63;
            int fi = dcol >> 1;
            float sgn = (dcol & 1) ? 1.f : -1.f;
            bf16* dstb = qk ? Kb : Qb;
#pragma unroll
            for (int r = 0; r < 4; ++r) {
                int rowg = bm + wr + m * 16 + hi * 4 + r;
                int pos = rowg & 1023, bidx = rowg >> 10;
                float val = acc[m][n][r] + bv;
                float part = __shfl_xor(val, 1);
                float cv = cost[pos * 32 + fi], sv = sint[pos * 32 + fi];
                float outv = val * cv + sgn * part * sv;
                dstb[(((size_t)(bidx * 16 + h)) * 1024 + pos) * 64 + dcol] = (bf16)outv;
            }
        }
    }
}

// ---------------- GEMM2: logits[b,h] = Q_bh @ K_bh^T, mask + scale ----------
// R12-exact: grid = 36 non-causal tiles x 128 bh; swizzled stage+frag reads;
// swapped operands (A=K,B=Q); LDS-transpose epilogue -> contiguous f32x4 nt
// stores; XCD-aware bh partition.
__global__ __launch_bounds__(256) void k_gemm2(
    const bf16* __restrict__ Qb, const bf16* __restrict__ Kb,
    const float* __restrict__ smask, float* __restrict__ out)
{
    __shared__ __align__(16) char smem[33792];
    bf16* lQ = (bf16*)smem;                    // 16 KB (MFMA phase)
    bf16* lK = (bf16*)(smem + 16384);          // 16 KB (MFMA phase)
    float* ldsF = (float*)smem;                // 32 KB (epilogue, reuse)
    float* npen_l = (float*)(smem + 32768);    // 128 f32
    float* mpen_l = (float*)(smem + 33280);    // 128 f32

    const int t = threadIdx.x;
    const int lane = t & 63, wave = t >> 6;
    const int wm = (wave >> 1) * 64, wn = (wave & 1) * 64;
    const int bid = (int)blockIdx.x;        // 4608 = 8 xcd * 16 bh * 36 tiles
    const int xcd = bid & 7;
    const int idx0 = bid >> 3;
    const int bh = xcd * 16 + (idx0 & 15);
    int rem36 = idx0 >> 4;                  // 0..35 -> (tm, tn>=tm)
    int tm = 0;
    while (rem36 >= 8 - tm) { rem36 -= 8 - tm; ++tm; }
    const int tn = tm + rem36;
    const int bm = tm * 128;
    const int bn = tn * 128;
    const int b = bh >> 4;
    const int rl = lane & 15, hi = lane >> 4;
    const float NINF = 1.25e11f;

    if (t < 128) npen_l[t] = 1.f - smask[b * 1024 + bn + t];
    else         mpen_l[t - 128] = 1.f - smask[b * 1024 + bm + (t - 128)];

    const size_t qoff = (size_t)bh * 1024 * 64;
#pragma unroll
    for (int p = 0; p < 4; ++p) {
        int e = t * 8 + p * 2048;
        int gr = e >> 3;
        int row = gr >> 3, c16 = gr & 7;
        int se = (row << 6) + ((c16 ^ (row & 7)) << 3);   // pre-swizzled source
        __builtin_amdgcn_global_load_lds(GL(Qb + qoff + (size_t)bm * 64 + se), LD(&lQ[e]), 16, 0, 0);
        __builtin_amdgcn_global_load_lds(GL(Kb + qoff + (size_t)bn * 64 + se), LD(&lK[e]), 16, 0, 0);
    }
    __syncthreads();

    f32x4 acc[4][4] = {};   // [i = col-frag (K)][j = row-frag (Q)]
#pragma unroll
    for (int ks = 0; ks < 2; ++ks) {
        bf16x8 af[4], bq[4];
#pragma unroll
        for (int i = 0; i < 4; ++i) {
            int R = wn + i * 16 + rl;
            af[i] = *(const bf16x8*)&lK[(R << 6) + ((((ks << 2) + hi) ^ (R & 7)) << 3)];
        }
#pragma unroll
        for (int j = 0; j < 4; ++j) {
            int Rq = wm + j * 16 + rl;
            bq[j] = *(const bf16x8*)&lQ[(Rq << 6) + ((((ks << 2) + hi) ^ (Rq & 7)) << 3)];
        }
#pragma unroll
        for (int i = 0; i < 4; ++i)
#pragma unroll
            for (int j = 0; j < 4; ++j)
                acc[i][j] = __builtin_amdgcn_mfma_f32_16x16x32_bf16(af[i], bq[j], acc[i][j], 0, 0, 0);
    }
    __syncthreads();   // frag reads done; lQ/lK region now reusable as ldsF

    // value(i,j,lane,r): row = wm + j*16 + rl, col = wn + i*16 + hi*4 + r
    for (int P = 0; P < 2; ++P) {
        if ((wave >> 1) == P) {
#pragma unroll
            for (int i = 0; i < 4; ++i)
#pragma unroll
                for (int j = 0; j < 4; ++j) {
                    int lrow = j * 16 + rl;
                    int lcol4 = wn * 4 + i * 64 + hi * 16;   // byte offset in row
                    char* p = (char*)ldsF + (lrow << 9) + (lcol4 ^ ((lrow & 7) << 4));
                    *(f32x4*)p = acc[i][j];
                }
        }
        __syncthreads();
#pragma unroll
        for (int k = 0; k < 8; ++k) {
            int idx = k * 256 + t;
            int lr = idx >> 5, slot = idx & 31;
            f32x4 v = ((const f32x4*)ldsF)[idx];            // linear phys read
            int col = (((slot << 4) ^ ((lr & 7) << 4)) >> 2);
            int grow = bm + P * 64 + lr;
            int gcol = bn + col;
            float mp = mpen_l[P * 64 + lr];
            f32x4 np = *(const f32x4*)&npen_l[col];
            f32x4 vo;
#pragma unroll
            for (int r = 0; r < 4; ++r) {
                float pen = mp + np[r] + ((gcol + r < grow) ? 1.f : 0.f);
                vo[r] = v[r] * 0.125f - pen * NINF;
            }
            nt_store4(&out[((size_t)bh << 20) + ((size_t)grow << 10) + gcol], vo);
        }
        __syncthreads();
    }
}

extern "C" void kernel_launch(void* const* d_in, const int* in_sizes, int n_in,
                              void* d_out, int out_size, void* d_ws, size_t ws_size,
                              hipStream_t stream) {
    (void)in_sizes; (void)n_in; (void)out_size; (void)ws_size;
    const float* x    = (const float*)d_in[0];
    const float* W    = (const float*)d_in[1];
    const float* bias = (const float*)d_in[2];
    const float* sm   = (const float*)d_in[3];
    float* out = (float*)d_out;

    char* ws = (char*)d_ws;
    size_t o = 0;
    bf16* Xb = (bf16*)(ws + o); o += 8388608ull * 2;
    bf16* Wt = (bf16*)(ws + o); o += 2097152ull * 2;
    bf16* Qb = (bf16*)(ws + o); o += 8388608ull * 2;
    bf16* Kb = (bf16*)(ws + o); o += 8388608ull * 2;
    float* cost = (float*)(ws + o); o += 32768ull * 4;
    float* sint = (float*)(ws + o); o += 32768ull * 4;

    hipLaunchKernelGGL(k_prep, dim3(2688), dim3(256), 0, stream,
                       (const float4*)x, (bf16x4*)Xb, W, Wt, cost, sint);
    hipLaunchKernelGGL(k_gemm1, dim3(64, 16), dim3(256), 0, stream,
                       Xb, Wt, bias, cost, sint, Qb, Kb, sm, out);
    hipLaunchKernelGGL(k_gemm2, dim3(4608), dim3(256), 0, stream,
                       Qb, Kb, sm, out);
}